// Round 1
// baseline (4274.606 us; speedup 1.0000x reference)
//
#include <hip/hip_runtime.h>
#include <math.h>

// BVP Helmholtz-residual PINN: psi = MLP(4 -> 256 -> 256 -> 256 -> 2), tanh.
// Jet propagation of 7 streams per neuron: {v, dx, dy, dz, dxx, dyy, dzz}.
// One wave per point; lane owns 4 contiguous neurons x 7 streams in regs.
// Weights staged in LDS (transposed, K-chunks of 32); activations in LDS
// as [j][8] so 7 stream values come back as two broadcast b128 reads.

#define HN 256

__device__ __forceinline__ void fma4(float4& a, const float4& w, float s) {
    a.x = fmaf(w.x, s, a.x);
    a.y = fmaf(w.y, s, a.y);
    a.z = fmaf(w.z, s, a.z);
    a.w = fmaf(w.w, s, a.w);
}

__global__ __launch_bounds__(256, 2)
void bvp_kernel(const float* __restrict__ gx, const float* __restrict__ gy,
                const float* __restrict__ gz, const float* __restrict__ gf,
                const float* __restrict__ W1, const float* __restrict__ b1,
                const float* __restrict__ W2, const float* __restrict__ b2,
                const float* __restrict__ W3, const float* __restrict__ b3,
                const float* __restrict__ W4, const float* __restrict__ b4,
                float* __restrict__ out, int N)
{
    // Wt[j'][i]: transposed weight chunk, stride 260 (16B-aligned rows, breaks
    // power-of-2 store conflicts). Hb[wave][j][8]: 7 streams padded to 8.
    __shared__ __align__(16) float Wt[32][260];
    __shared__ __align__(16) float Hb[4][HN][8];

    const int tid  = threadIdx.x;
    const int wave = tid >> 6;
    const int lane = tid & 63;
    const int n    = blockIdx.x * 4 + wave;
    const bool valid = (n < N);
    const int nn = valid ? n : 0;

    const float xi = gx[nn], yi = gy[nn], zi = gz[nn], fi = gf[nn];

    // h[stream][kq]: lane's 4 neurons (i = 4*lane + kq), 7 streams
    float h[7][4];

    // ---------------- layer 1: u = W1 @ [x,y,z,f] + b1 ----------------
    #pragma unroll
    for (int kq = 0; kq < 4; ++kq) {
        const int i = 4 * lane + kq;
        const float4 w = *(const float4*)(W1 + 4 * i);
        const float u = fmaf(w.x, xi, fmaf(w.y, yi, fmaf(w.z, zi, fmaf(w.w, fi, b1[i]))));
        const float t  = tanhf(u);
        const float sg = 1.f - t * t;
        const float c  = -2.f * t * sg;
        h[0][kq] = t;
        h[1][kq] = sg * w.x;      // u' along x is W1[:,0]; u'' = 0
        h[2][kq] = sg * w.y;
        h[3][kq] = sg * w.z;
        h[4][kq] = c * w.x * w.x;
        h[5][kq] = c * w.y * w.y;
        h[6][kq] = c * w.z * w.z;
    }

    // ---------------- hidden layers 2 and 3 ----------------
    for (int layer = 0; layer < 2; ++layer) {
        const float* __restrict__ W = layer ? W3 : W2;
        const float* __restrict__ b = layer ? b3 : b2;

        // stage this wave's 7-stream activation vector into LDS ([j][8] layout)
        #pragma unroll
        for (int kq = 0; kq < 4; ++kq) {
            const int j = 4 * lane + kq;
            *(float4*)&Hb[wave][j][0] = make_float4(h[0][kq], h[1][kq], h[2][kq], h[3][kq]);
            *(float4*)&Hb[wave][j][4] = make_float4(h[4][kq], h[5][kq], h[6][kq], 0.f);
        }

        float4 acc0 = make_float4(0.f, 0.f, 0.f, 0.f);
        float4 acc1 = acc0, acc2 = acc0, acc3 = acc0, acc4 = acc0, acc5 = acc0, acc6 = acc0;

        for (int kc = 0; kc < HN; kc += 32) {
            __syncthreads();   // previous chunk's Wt reads (all waves) done
            // cooperative transpose-stage: W[i][kc..kc+31] -> Wt[j'][i]
            // 2048 float4s per chunk / 256 threads = 8 each; 8 threads per row
            // (128B contiguous per 8 lanes -> coalesced-ish, full cache lines)
            {
                const float4* __restrict__ Wv = (const float4*)W;
                const int c = tid & 7;            // which float4 within the 32-col chunk
                #pragma unroll
                for (int q = 0; q < 8; ++q) {
                    const int i = (q << 5) + (tid >> 3);
                    const float4 v = Wv[i * (HN / 4) + (kc >> 2) + c];
                    Wt[4 * c + 0][i] = v.x;
                    Wt[4 * c + 1][i] = v.y;
                    Wt[4 * c + 2][i] = v.z;
                    Wt[4 * c + 3][i] = v.w;
                }
            }
            __syncthreads();

            #pragma unroll 8
            for (int jj = 0; jj < 32; ++jj) {
                const int j = kc + jj;
                const float4 w  = *(const float4*)&Wt[jj][4 * lane];
                const float4 hA = *(const float4*)&Hb[wave][j][0];  // v,dx,dy,dz (broadcast)
                const float4 hB = *(const float4*)&Hb[wave][j][4];  // dxx,dyy,dzz (broadcast)
                fma4(acc0, w, hA.x);
                fma4(acc1, w, hA.y);
                fma4(acc2, w, hA.z);
                fma4(acc3, w, hA.w);
                fma4(acc4, w, hB.x);
                fma4(acc5, w, hB.y);
                fma4(acc6, w, hB.z);
            }
        }

        // tanh jet: h' = s u';  h'' = s u'' - 2 t s (u')^2
        const float accv[7][4] = {
            {acc0.x, acc0.y, acc0.z, acc0.w}, {acc1.x, acc1.y, acc1.z, acc1.w},
            {acc2.x, acc2.y, acc2.z, acc2.w}, {acc3.x, acc3.y, acc3.z, acc3.w},
            {acc4.x, acc4.y, acc4.z, acc4.w}, {acc5.x, acc5.y, acc5.z, acc5.w},
            {acc6.x, acc6.y, acc6.z, acc6.w}};
        #pragma unroll
        for (int kq = 0; kq < 4; ++kq) {
            const int i = 4 * lane + kq;
            const float u  = accv[0][kq] + b[i];
            const float t  = tanhf(u);
            const float sg = 1.f - t * t;
            const float c  = -2.f * t * sg;
            const float ux = accv[1][kq], uy = accv[2][kq], uz = accv[3][kq];
            h[0][kq] = t;
            h[1][kq] = sg * ux;
            h[2][kq] = sg * uy;
            h[3][kq] = sg * uz;
            h[4][kq] = fmaf(sg, accv[4][kq], c * ux * ux);
            h[5][kq] = fmaf(sg, accv[5][kq], c * uy * uy);
            h[6][kq] = fmaf(sg, accv[6][kq], c * uz * uz);
        }
    }

    // ---------------- layer 4: need streams {v, dxx, dyy, dzz} x 2 outputs ----
    float part[8] = {0.f, 0.f, 0.f, 0.f, 0.f, 0.f, 0.f, 0.f};
    #pragma unroll
    for (int kq = 0; kq < 4; ++kq) {
        const int i = 4 * lane + kq;
        const float w0 = W4[i];          // row 0 (real)
        const float w1 = W4[HN + i];     // row 1 (imag)
        part[0] = fmaf(w0, h[0][kq], part[0]);
        part[1] = fmaf(w0, h[4][kq], part[1]);
        part[2] = fmaf(w0, h[5][kq], part[2]);
        part[3] = fmaf(w0, h[6][kq], part[3]);
        part[4] = fmaf(w1, h[0][kq], part[4]);
        part[5] = fmaf(w1, h[4][kq], part[5]);
        part[6] = fmaf(w1, h[5][kq], part[6]);
        part[7] = fmaf(w1, h[6][kq], part[7]);
    }
    #pragma unroll
    for (int off = 32; off > 0; off >>= 1) {
        #pragma unroll
        for (int q = 0; q < 8; ++q)
            part[q] += __shfl_down(part[q], off, 64);
    }

    if (lane == 0 && valid) {
        const float PI  = 3.14159265358979323846f;
        const float kw  = 2.f * PI * (fi * 500.f + 100.f) / 343.f;
        const float vol = 0.7f * 0.5f * 0.6f;                // XC*YC*ZC
        const float kk  = vol * vol * kw * kw;
        const float cxx = (0.5f * 0.6f) * (0.5f * 0.6f);     // (YC*ZC)^2
        const float cyy = (0.7f * 0.6f) * (0.7f * 0.6f);     // (XC*ZC)^2
        const float czz = (0.7f * 0.5f) * (0.7f * 0.5f);     // (XC*YC)^2
        const float pr = part[0] + b4[0];
        const float pi = part[4] + b4[1];
        const float rre = 2.0f * (cxx * part[1] + cyy * part[2] + czz * part[3])
                          + kk * (pr * 2.0f + 0.1f);
        const float rim = 1.5f * (cxx * part[5] + cyy * part[6] + czz * part[7])
                          + kk * (pi * 1.5f - 0.05f);
        out[n]     = rre;
        out[N + n] = rim;
    }
}

extern "C" void kernel_launch(void* const* d_in, const int* in_sizes, int n_in,
                              void* d_out, int out_size, void* d_ws, size_t ws_size,
                              hipStream_t stream) {
    const float* x  = (const float*)d_in[0];
    const float* y  = (const float*)d_in[1];
    const float* z  = (const float*)d_in[2];
    const float* f  = (const float*)d_in[3];
    const float* W1 = (const float*)d_in[4];
    const float* b1 = (const float*)d_in[5];
    const float* W2 = (const float*)d_in[6];
    const float* b2 = (const float*)d_in[7];
    const float* W3 = (const float*)d_in[8];
    const float* b3 = (const float*)d_in[9];
    const float* W4 = (const float*)d_in[10];
    const float* b4 = (const float*)d_in[11];
    float* out = (float*)d_out;
    const int N = in_sizes[0];
    const int nblocks = (N + 3) / 4;
    hipLaunchKernelGGL(bvp_kernel, dim3(nblocks), dim3(256), 0, stream,
                       x, y, z, f, W1, b1, W2, b2, W3, b3, W4, b4, out, N);
}

// Round 2
// 1680.333 us; speedup vs baseline: 2.5439x; 2.5439x over previous
//
#include <hip/hip_runtime.h>
#include <math.h>

// BVP Helmholtz-residual PINN via split-bf16 MFMA.
// psi = MLP(4 -> 256 -> 256 -> 256 -> 2), tanh. Jet propagation: 7 streams
// {v,dx,dy,dz,dxx,dyy,dzz} per neuron are 7 GEMM columns per point.
// Hidden layers = GEMM 256x256 @ 256x112 (P=16 points/block), 16x16x32 bf16
// MFMA, fp32-accurate via hi/lo bf16 split (Whi*Hhi + Whi*Hlo + Wlo*Hhi).

typedef __attribute__((ext_vector_type(8))) short short8;
typedef __attribute__((ext_vector_type(4))) float floatx4;
typedef unsigned short ushort_t;
typedef unsigned int uint_t;

#define PBLK 16
#define NCOLS 112                            // 7 streams * 16 points
#define NH 256
#define BSTRIDE 1040                         // bytes per B column (256k * 2 parts * 2B + 16 pad)
#define ASTRIDE 144                          // bytes per A row in a K-chunk (32k * 2 * 2B + 16 pad)
#define AREG_OFF (NCOLS * BSTRIDE)           // 116480
#define USTRIDE 68                           // floats per U column (64 rows + 4 pad)
#define LDS_BYTES (AREG_OFF + NH * ASTRIDE)  // 153344
#define WS_NEEDED (2 * NH * NH * 2 * 2)      // 524288 B: W2,W3 as (hi,lo) bf16

__device__ __forceinline__ ushort_t f2bf(float f) {
    uint_t u = __float_as_uint(f);
    return (ushort_t)((u + 0x7FFFu + ((u >> 16) & 1u)) >> 16);  // RNE
}
__device__ __forceinline__ float bf2f(ushort_t h) {
    return __uint_as_float(((uint_t)h) << 16);
}
__device__ __forceinline__ float fast_tanh(float u) {
    float e = __expf(2.f * u);
    return 1.f - 2.f / (e + 1.f);   // exact limits at +-inf, NaN-free for finite u
}

// ws layout per layer (262144 B): byte = kc*32768 + row*128 + q*32 + part*16 + j*2
// with k = kc*32 + q*8 + j  (matches MFMA A-frag: m=lane&15 row, k=quad*8+j)
__global__ void prep_split(const float* __restrict__ W2, const float* __restrict__ W3,
                           ushort_t* __restrict__ ws) {
    int t = blockIdx.x * blockDim.x + threadIdx.x;   // 0..16383
    const float* W = (t >> 13) ? W3 : W2;
    int r = t & 8191;
    int row = r >> 5, grp = r & 31;                  // grp = 8 consecutive k's
    const float4* Wv = (const float4*)(W + row * 256 + grp * 8);
    float4 a4 = Wv[0], b4v = Wv[1];
    float v[8] = {a4.x, a4.y, a4.z, a4.w, b4v.x, b4v.y, b4v.z, b4v.w};
    short8 h8, l8;
    #pragma unroll
    for (int j = 0; j < 8; ++j) {
        ushort_t hi = f2bf(v[j]);
        h8[j] = (short)hi;
        l8[j] = (short)f2bf(v[j] - bf2f(hi));
    }
    size_t base = (size_t)(t >> 13) * 262144 + (size_t)(grp >> 2) * 32768
                + (size_t)row * 128 + (size_t)(grp & 3) * 32;
    *(short8*)((char*)ws + base) = h8;
    *(short8*)((char*)ws + base + 16) = l8;
}

template <bool USE_WS>
__global__ __launch_bounds__(512)
void bvp_main(const float* __restrict__ gx, const float* __restrict__ gy,
              const float* __restrict__ gz, const float* __restrict__ gf,
              const float* __restrict__ W1, const float* __restrict__ b1,
              const float* __restrict__ W2, const float* __restrict__ b2,
              const float* __restrict__ W3, const float* __restrict__ b3,
              const float* __restrict__ W4, const float* __restrict__ b4,
              const uint4* __restrict__ wsv, float* __restrict__ out, int N) {
    extern __shared__ char smem[];
    char* const Areg = smem + AREG_OFF;           // W K-chunk (also U scratch)
    float* const Uf = (float*)(smem + AREG_OFF);  // u round-trip, [col][68]

    const int tid = threadIdx.x;
    const int wave = tid >> 6, lane = tid & 63;
    const int q = lane >> 4, n15 = lane & 15;
    const int p = tid >> 5, tl = tid & 31;        // jet-phase: point, row-pair id
    const int pbase = blockIdx.x * PBLK;
    const int pidx = min(pbase + p, N - 1);

    const float4* Wv2 = (const float4*)W2;
    const float4* Wv3 = (const float4*)W3;
    const uint4* ws2 = wsv;
    const uint4* ws3 = wsv + 16384;

    uint4 pf[4];  // register prefetch of next W chunk (64 B/thread)

    auto prefetch = [&](const uint4* wsl, const float4* Wl, int kc) {
        if constexpr (USE_WS) {
            #pragma unroll
            for (int s = 0; s < 4; ++s) pf[s] = wsl[kc * 2048 + tid * 4 + s];
        } else {
            #pragma unroll
            for (int s = 0; s < 4; ++s) {
                int v = tid * 4 + s, row = v >> 3, kq = v & 7;
                float4 t4 = Wl[row * 64 + kc * 8 + kq];
                pf[s] = *(uint4*)&t4;
            }
        }
    };
    auto store_a = [&]() {
        if constexpr (USE_WS) {
            #pragma unroll
            for (int s = 0; s < 4; ++s) {
                int v = tid * 4 + s, row = v >> 3, sub = v & 7;
                *(uint4*)(Areg + row * ASTRIDE + sub * 16) = pf[s];
            }
        } else {
            #pragma unroll
            for (int s = 0; s < 4; ++s) {
                int v = tid * 4 + s, row = v >> 3, kq = v & 7;
                float4 f4 = *(float4*)&pf[s];
                float vv[4] = {f4.x, f4.y, f4.z, f4.w};
                ushort_t hi[4], lo[4];
                #pragma unroll
                for (int j = 0; j < 4; ++j) {
                    hi[j] = f2bf(vv[j]);
                    lo[j] = f2bf(vv[j] - bf2f(hi[j]));
                }
                char* dst = Areg + row * ASTRIDE + (kq >> 1) * 32 + (kq & 1) * 8;
                *(ushort4*)dst = make_ushort4(hi[0], hi[1], hi[2], hi[3]);
                *(ushort4*)(dst + 16) = make_ushort4(lo[0], lo[1], lo[2], lo[3]);
            }
        }
    };

    floatx4 acc[2][7];  // wave tile: 2 row-tiles (32 rows) x 7 col-tiles (112 cols)
    auto zero_acc = [&]() {
        #pragma unroll
        for (int rt = 0; rt < 2; ++rt)
            #pragma unroll
            for (int ct = 0; ct < 7; ++ct)
                acc[rt][ct] = (floatx4){0.f, 0.f, 0.f, 0.f};
    };

    auto gemm = [&](const uint4* wsl, const float4* Wl) {
        #pragma unroll 1
        for (int kc = 0; kc < 8; ++kc) {
            __syncthreads();            // prior chunk's frag reads done
            store_a();
            __syncthreads();            // A chunk visible
            if (kc < 7) prefetch(wsl, Wl, kc + 1);   // overlap with MFMA
            short8 afr[2][2];
            #pragma unroll
            for (int rt = 0; rt < 2; ++rt) {
                const char* ap = Areg + (wave * 32 + rt * 16 + n15) * ASTRIDE + q * 32;
                afr[rt][0] = *(const short8*)ap;        // hi
                afr[rt][1] = *(const short8*)(ap + 16); // lo
            }
            #pragma unroll
            for (int ct = 0; ct < 7; ++ct) {
                const char* bp = smem + (ct * 16 + n15) * BSTRIDE + (kc * 4 + q) * 32;
                short8 bh = *(const short8*)bp;
                short8 bl = *(const short8*)(bp + 16);
                #pragma unroll
                for (int rt = 0; rt < 2; ++rt) {
                    acc[rt][ct] = __builtin_amdgcn_mfma_f32_16x16x32_bf16(afr[rt][0], bh, acc[rt][ct], 0, 0, 0);
                    acc[rt][ct] = __builtin_amdgcn_mfma_f32_16x16x32_bf16(afr[rt][0], bl, acc[rt][ct], 0, 0, 0);
                    acc[rt][ct] = __builtin_amdgcn_mfma_f32_16x16x32_bf16(afr[rt][1], bh, acc[rt][ct], 0, 0, 0);
                }
            }
        }
    };

    // C/D layout: col = lane&15, row = quad*4 + reg  ->  float4 regs are 4
    // consecutive rows: store column-major into Uf[col][68].
    auto dump_acc = [&](int g) {
        if ((wave >> 1) == g) {
            const int rlbase = (wave & 1) * 32;
            #pragma unroll
            for (int rt = 0; rt < 2; ++rt)
                #pragma unroll
                for (int ct = 0; ct < 7; ++ct)
                    *(floatx4*)&Uf[(ct * 16 + n15) * USTRIDE + rlbase + rt * 16 + q * 4] = acc[rt][ct];
        }
    };
    auto jet7 = [&](const float u[7], float h[7]) {
        float t = fast_tanh(u[0]);
        float s = 1.f - t * t;
        float c = -2.f * t * s;
        h[0] = t;
        h[1] = s * u[1]; h[2] = s * u[2]; h[3] = s * u[3];
        h[4] = fmaf(s, u[4], c * u[1] * u[1]);
        h[5] = fmaf(s, u[5], c * u[2] * u[2]);
        h[6] = fmaf(s, u[6], c * u[3] * u[3]);
    };

    // ---------------- layer 1 (VALU) -> B ----------------
    prefetch(ws2, Wv2, 0);   // W2 chunk 0 in flight during layer 1
    {
        const float xi = gx[pidx], yi = gy[pidx], zi = gz[pidx], fi1 = gf[pidx];
        const int i0 = tl * 8;
        float hv[8][7];
        #pragma unroll
        for (int r = 0; r < 8; ++r) {
            const int i = i0 + r;
            float4 w = *(const float4*)(W1 + 4 * i);
            float u = fmaf(w.x, xi, fmaf(w.y, yi, fmaf(w.z, zi, fmaf(w.w, fi1, b1[i]))));
            float t = fast_tanh(u);
            float s = 1.f - t * t;
            float c = -2.f * t * s;
            hv[r][0] = t;
            hv[r][1] = s * w.x; hv[r][2] = s * w.y; hv[r][3] = s * w.z;
            hv[r][4] = c * w.x * w.x; hv[r][5] = c * w.y * w.y; hv[r][6] = c * w.z * w.z;
        }
        #pragma unroll
        for (int s = 0; s < 7; ++s) {
            short8 h8, l8;
            #pragma unroll
            for (int r = 0; r < 8; ++r) {
                ushort_t hb = f2bf(hv[r][s]);
                h8[r] = (short)hb;
                l8[r] = (short)f2bf(hv[r][s] - bf2f(hb));
            }
            char* bp = smem + (7 * p + s) * BSTRIDE + tl * 32;
            *(short8*)bp = h8;
            *(short8*)(bp + 16) = l8;
        }
    }

    // ---------------- GEMM 2 ----------------
    zero_acc();
    gemm(ws2, Wv2);
    prefetch(ws3, Wv3, 0);   // W3 chunk 0 in flight during jet-2

    // ---------------- jet 2: u2 -> h2 -> B (in place) ----------------
    #pragma unroll 1
    for (int g = 0; g < 4; ++g) {
        __syncthreads();
        dump_acc(g);
        __syncthreads();
        const int i0 = g * 64 + tl * 2;
        float ua[7], ub[7];
        #pragma unroll
        for (int s = 0; s < 7; ++s) {
            float2 t2 = *(float2*)&Uf[(7 * p + s) * USTRIDE + tl * 2];
            ua[s] = t2.x; ub[s] = t2.y;
        }
        ua[0] += b2[i0]; ub[0] += b2[i0 + 1];   // bias only on value stream
        float ha[7], hb[7];
        jet7(ua, ha); jet7(ub, hb);
        #pragma unroll
        for (int s = 0; s < 7; ++s) {
            ushort_t h0 = f2bf(ha[s]), h1 = f2bf(hb[s]);
            ushort_t l0 = f2bf(ha[s] - bf2f(h0)), l1 = f2bf(hb[s] - bf2f(h1));
            char* bp = smem + (7 * p + s) * BSTRIDE + (i0 >> 3) * 32 + (i0 & 7) * 2;
            *(uint_t*)bp = (uint_t)h0 | ((uint_t)h1 << 16);
            *(uint_t*)(bp + 16) = (uint_t)l0 | ((uint_t)l1 << 16);
        }
    }

    // ---------------- GEMM 3 ----------------
    zero_acc();
    gemm(ws3, Wv3);

    // ---------------- jet 3 + layer 4 partials ----------------
    float part[8] = {0.f, 0.f, 0.f, 0.f, 0.f, 0.f, 0.f, 0.f};
    #pragma unroll 1
    for (int g = 0; g < 4; ++g) {
        __syncthreads();
        dump_acc(g);
        __syncthreads();
        const int i0 = g * 64 + tl * 2;
        float ua[7], ub[7];
        #pragma unroll
        for (int s = 0; s < 7; ++s) {
            float2 t2 = *(float2*)&Uf[(7 * p + s) * USTRIDE + tl * 2];
            ua[s] = t2.x; ub[s] = t2.y;
        }
        ua[0] += b3[i0]; ub[0] += b3[i0 + 1];
        float ha[7], hb[7];
        jet7(ua, ha); jet7(ub, hb);
        const float w0a = W4[i0], w0b = W4[i0 + 1];
        const float w1a = W4[NH + i0], w1b = W4[NH + i0 + 1];
        part[0] += w0a * ha[0] + w0b * hb[0];
        part[1] += w0a * ha[4] + w0b * hb[4];
        part[2] += w0a * ha[5] + w0b * hb[5];
        part[3] += w0a * ha[6] + w0b * hb[6];
        part[4] += w1a * ha[0] + w1b * hb[0];
        part[5] += w1a * ha[4] + w1b * hb[4];
        part[6] += w1a * ha[5] + w1b * hb[5];
        part[7] += w1a * ha[6] + w1b * hb[6];
    }

    // reduce the 32 threads sharing a point, then finalize
    #pragma unroll
    for (int off = 16; off >= 1; off >>= 1)
        #pragma unroll
        for (int k = 0; k < 8; ++k)
            part[k] += __shfl_xor(part[k], off, 32);

    if (tl == 0 && (pbase + p) < N) {
        const int n = pbase + p;
        const float fi = gf[n];
        const float PI = 3.14159265358979323846f;
        const float kw = 2.f * PI * (fi * 500.f + 100.f) / 343.f;
        const float vol = 0.7f * 0.5f * 0.6f;
        const float kk = vol * vol * kw * kw;
        const float cxx = (0.5f * 0.6f) * (0.5f * 0.6f);
        const float cyy = (0.7f * 0.6f) * (0.7f * 0.6f);
        const float czz = (0.7f * 0.5f) * (0.7f * 0.5f);
        const float pr = part[0] + b4[0];
        const float pim = part[4] + b4[1];
        out[n] = 2.0f * (cxx * part[1] + cyy * part[2] + czz * part[3]) + kk * (pr * 2.0f + 0.1f);
        out[N + n] = 1.5f * (cxx * part[5] + cyy * part[6] + czz * part[7]) + kk * (pim * 1.5f - 0.05f);
    }
}

extern "C" void kernel_launch(void* const* d_in, const int* in_sizes, int n_in,
                              void* d_out, int out_size, void* d_ws, size_t ws_size,
                              hipStream_t stream) {
    const float* x = (const float*)d_in[0];
    const float* y = (const float*)d_in[1];
    const float* z = (const float*)d_in[2];
    const float* f = (const float*)d_in[3];
    const float* W1 = (const float*)d_in[4];
    const float* b1 = (const float*)d_in[5];
    const float* W2 = (const float*)d_in[6];
    const float* b2 = (const float*)d_in[7];
    const float* W3 = (const float*)d_in[8];
    const float* b3 = (const float*)d_in[9];
    const float* W4 = (const float*)d_in[10];
    const float* b4 = (const float*)d_in[11];
    float* out = (float*)d_out;
    const int N = in_sizes[0];
    const int grid = (N + PBLK - 1) / PBLK;
    const bool use_ws = (ws_size >= (size_t)WS_NEEDED);

    if (use_ws) {
        prep_split<<<64, 256, 0, stream>>>(W2, W3, (ushort_t*)d_ws);
        const void* kf = reinterpret_cast<const void*>(&bvp_main<true>);
        (void)hipFuncSetAttribute(kf, hipFuncAttributeMaxDynamicSharedMemorySize, LDS_BYTES);
        bvp_main<true><<<grid, 512, LDS_BYTES, stream>>>(
            x, y, z, f, W1, b1, W2, b2, W3, b3, W4, b4, (const uint4*)d_ws, out, N);
    } else {
        const void* kf = reinterpret_cast<const void*>(&bvp_main<false>);
        (void)hipFuncSetAttribute(kf, hipFuncAttributeMaxDynamicSharedMemorySize, LDS_BYTES);
        bvp_main<false><<<grid, 512, LDS_BYTES, stream>>>(
            x, y, z, f, W1, b1, W2, b2, W3, b3, W4, b4, (const uint4*)d_ws, out, N);
    }
}

// Round 3
// 511.701 us; speedup vs baseline: 8.3537x; 3.2838x over previous
//
#include <hip/hip_runtime.h>
#include <math.h>

// BVP Helmholtz-residual PINN via MFMA, round 3.
// psi = MLP(4 -> 256 -> 256 -> 256 -> 2), tanh. Jet propagation: 7 streams
// {v,dx,dy,dz,dxx,dyy,dzz} per point = 7 GEMM columns, col = s*16 + p.
// Key structure:
//  - A (weights) pre-split hi/lo bf16 in d_ws in A-fragment order; read
//    straight from L2 into registers -> NO barriers in the K-loop.
//  - k-order inside each 32-k-tile permuted as k(q,j)=16(j>>2)+4q+(j&3):
//    each lane's C accumulators pack directly into its own B fragment
//    (jet + repack 100% lane-local; W3 columns permuted to match in prep).
//  - 2-term split: U = Whi*Hbf + Wlo*Hbf (H single bf16). ~2^-10 rel/layer,
//    threshold is ~2% relative -> passes with margin.
// 4 waves/block, 64 rows/wave, 16 points/block. LDS 59.4 KB -> 2 blocks/CU.

typedef __attribute__((ext_vector_type(8))) short short8;
typedef __attribute__((ext_vector_type(4))) float floatx4;
typedef unsigned short ushort_t;
typedef unsigned int uint_t;

#define PBLK 16
#define WS_NEEDED 524288

__device__ __forceinline__ ushort_t f2bf(float f) {
    uint_t u = __float_as_uint(f);
    return (ushort_t)((u + 0x7FFFu + ((u >> 16) & 1u)) >> 16);  // RNE
}
__device__ __forceinline__ float bf2f(ushort_t h) {
    return __uint_as_float(((uint_t)h) << 16);
}
__device__ __forceinline__ float fast_tanh(float u) {
    float e = __expf(2.f * u);
    return 1.f - 2.f / (e + 1.f);   // exact at +-inf for finite u
}

// ws: 2 layers x 16 row-tiles x 8 kc x 2 parts x 64 lanes x 16B = 512 KB.
// A-frag lane (m=lane&15, qa=lane>>4) slot j:
//   layer0 (W2, natural):  col = kc*32 + 8*qa + j
//   layer1 (W3, permuted): col = kc*32 + 16*(j>>2) + 4*qa + (j&3)
__global__ void prep_split(const float* __restrict__ W2, const float* __restrict__ W3,
                           short8* __restrict__ ws) {
    int t16 = blockIdx.x * blockDim.x + threadIdx.x;  // 0..16383
    int lane = t16 & 63;
    int kc = (t16 >> 6) & 7;
    int tt = (t16 >> 9) & 15;
    int l = t16 >> 13;
    const float* W = l ? W3 : W2;
    int row = tt * 16 + (lane & 15);
    int qa = lane >> 4;
    const float* src = W + row * 256 + kc * 32 + (l ? 4 * qa : 8 * qa);
    float4 va = *(const float4*)src;
    float4 vb = *(const float4*)(src + (l ? 16 : 4));
    float v[8] = {va.x, va.y, va.z, va.w, vb.x, vb.y, vb.z, vb.w};
    short8 hi8, lo8;
    #pragma unroll
    for (int j = 0; j < 8; ++j) {
        ushort_t h = f2bf(v[j]);
        hi8[j] = (short)h;
        lo8[j] = (short)f2bf(v[j] - bf2f(h));
    }
    int base = l * 16384 + tt * 1024 + kc * 128 + lane;
    ws[base] = hi8;        // part 0 = hi
    ws[base + 64] = lo8;   // part 1 = lo
}

__global__ __launch_bounds__(256, 2)
void bvp_main(const float* __restrict__ gx, const float* __restrict__ gy,
              const float* __restrict__ gz, const float* __restrict__ gf,
              const float* __restrict__ W1, const float* __restrict__ b1,
              const float* __restrict__ b2, const float* __restrict__ b3,
              const float* __restrict__ W4, const float* __restrict__ b4,
              const short8* __restrict__ wsA, float* __restrict__ out, int N) {
    __shared__ short8 Bsh[7 * 8 * 64];   // 57344 B: B[s][kt][lane]
    __shared__ float red[4][16][8];      // 2 KB cross-wave reduction scratch

    const int tid = threadIdx.x;
    const int w = tid >> 6, lane = tid & 63;
    const int p = lane & 15, qc = lane >> 4;
    const int pbase = blockIdx.x * PBLK;

    // ---------------- layer 1 (VALU) -> B fragments ----------------
    {
        const int pp = tid >> 4, u8 = tid & 15;
        const int pidx = min(pbase + pp, N - 1);
        const float xi = gx[pidx], yi = gy[pidx], zi = gz[pidx], fi = gf[pidx];
        #pragma unroll
        for (int g = 0; g < 2; ++g) {
            float hv[7][8];
            #pragma unroll
            for (int r = 0; r < 8; ++r) {
                const int i = u8 * 16 + g * 8 + r;
                float4 wv = *(const float4*)(W1 + 4 * i);
                float u = fmaf(wv.x, xi, fmaf(wv.y, yi, fmaf(wv.z, zi, fmaf(wv.w, fi, b1[i]))));
                float t = fast_tanh(u), s = 1.f - t * t, c = -2.f * t * s;
                hv[0][r] = t;
                hv[1][r] = s * wv.x; hv[2][r] = s * wv.y; hv[3][r] = s * wv.z;
                hv[4][r] = c * wv.x * wv.x; hv[5][r] = c * wv.y * wv.y; hv[6][r] = c * wv.z * wv.z;
            }
            const int u2 = u8 * 2 + g;               // neurons 8*u2..8*u2+7
            const int kt = u2 >> 2, q = u2 & 3, ln = q * 16 + pp;
            #pragma unroll
            for (int s = 0; s < 7; ++s) {
                short8 v;
                #pragma unroll
                for (int r = 0; r < 8; ++r) v[r] = (short)f2bf(hv[s][r]);
                Bsh[(s * 8 + kt) * 64 + ln] = v;
            }
        }
    }
    __syncthreads();

    floatx4 acc[4][7];   // 4 row-tiles (64 rows) x 7 streams

    auto run_gemm = [&](const short8* __restrict__ A) {
        #pragma unroll
        for (int rt = 0; rt < 4; ++rt)
            #pragma unroll
            for (int ct = 0; ct < 7; ++ct) acc[rt][ct] = (floatx4){0.f, 0.f, 0.f, 0.f};
        short8 a[8];
        #pragma unroll
        for (int rp = 0; rp < 8; ++rp)
            a[rp] = A[(4 * w + (rp >> 1)) * 1024 + (rp & 1) * 64 + lane];   // kc=0
        #pragma unroll
        for (int kc = 0; kc < 8; ++kc) {
            short8 an[8];
            if (kc < 7) {
                #pragma unroll
                for (int rp = 0; rp < 8; ++rp)
                    an[rp] = A[(4 * w + (rp >> 1)) * 1024 + (kc + 1) * 128 + (rp & 1) * 64 + lane];
            }
            short8 b[7];
            #pragma unroll
            for (int ct = 0; ct < 7; ++ct) b[ct] = Bsh[(ct * 8 + kc) * 64 + lane];
            #pragma unroll
            for (int ct = 0; ct < 7; ++ct)
                #pragma unroll
                for (int rt = 0; rt < 4; ++rt) {
                    acc[rt][ct] = __builtin_amdgcn_mfma_f32_16x16x32_bf16(a[rt * 2], b[ct], acc[rt][ct], 0, 0, 0);
                    acc[rt][ct] = __builtin_amdgcn_mfma_f32_16x16x32_bf16(a[rt * 2 + 1], b[ct], acc[rt][ct], 0, 0, 0);
                }
            if (kc < 7) {
                #pragma unroll
                for (int rp = 0; rp < 8; ++rp) a[rp] = an[rp];
            }
        }
    };

    // ---------------- GEMM 2 ----------------
    run_gemm(wsA);
    __syncthreads();   // all waves done reading layer-2 B

    // ---------------- jet 2 (lane-local) -> new B fragments ----------------
    #pragma unroll
    for (int rt = 0; rt < 4; ++rt) {
        const float4 bb = *(const float4*)(b2 + w * 64 + rt * 16 + qc * 4);
        const float bbv[4] = {bb.x, bb.y, bb.z, bb.w};
        #pragma unroll
        for (int r = 0; r < 4; ++r) {
            float t = fast_tanh(acc[rt][0][r] + bbv[r]);
            float s = 1.f - t * t, c = -2.f * t * s;
            float ux = acc[rt][1][r], uy = acc[rt][2][r], uz = acc[rt][3][r];
            acc[rt][0][r] = t;
            acc[rt][1][r] = s * ux; acc[rt][2][r] = s * uy; acc[rt][3][r] = s * uz;
            acc[rt][4][r] = fmaf(s, acc[rt][4][r], c * ux * ux);
            acc[rt][5][r] = fmaf(s, acc[rt][5][r], c * uy * uy);
            acc[rt][6][r] = fmaf(s, acc[rt][6][r], c * uz * uz);
        }
    }
    #pragma unroll
    for (int hh = 0; hh < 2; ++hh)
        #pragma unroll
        for (int s = 0; s < 7; ++s) {
            short8 v;
            #pragma unroll
            for (int r = 0; r < 4; ++r) {
                v[r]     = (short)f2bf(acc[2 * hh][s][r]);
                v[4 + r] = (short)f2bf(acc[2 * hh + 1][s][r]);
            }
            Bsh[(s * 8 + 2 * w + hh) * 64 + lane] = v;   // kt = 2w+hh, own lane slot
        }
    __syncthreads();

    // ---------------- GEMM 3 ----------------
    run_gemm(wsA + 16384);

    // ---------------- jet 3 + layer-4 partials (lane-local) ----------------
    float pt[8] = {0.f, 0.f, 0.f, 0.f, 0.f, 0.f, 0.f, 0.f};
    #pragma unroll
    for (int rt = 0; rt < 4; ++rt) {
        const int rb = w * 64 + rt * 16 + qc * 4;
        const float4 bb = *(const float4*)(b3 + rb);
        const float4 w0 = *(const float4*)(W4 + rb);
        const float4 w1 = *(const float4*)(W4 + 256 + rb);
        const float bbv[4] = {bb.x, bb.y, bb.z, bb.w};
        const float w0v[4] = {w0.x, w0.y, w0.z, w0.w};
        const float w1v[4] = {w1.x, w1.y, w1.z, w1.w};
        #pragma unroll
        for (int r = 0; r < 4; ++r) {
            float t = fast_tanh(acc[rt][0][r] + bbv[r]);
            float s = 1.f - t * t, c = -2.f * t * s;
            float ux = acc[rt][1][r], uy = acc[rt][2][r], uz = acc[rt][3][r];
            float hv = t;
            float hxx = fmaf(s, acc[rt][4][r], c * ux * ux);
            float hyy = fmaf(s, acc[rt][5][r], c * uy * uy);
            float hzz = fmaf(s, acc[rt][6][r], c * uz * uz);
            pt[0] = fmaf(w0v[r], hv, pt[0]);
            pt[1] = fmaf(w0v[r], hxx, pt[1]);
            pt[2] = fmaf(w0v[r], hyy, pt[2]);
            pt[3] = fmaf(w0v[r], hzz, pt[3]);
            pt[4] = fmaf(w1v[r], hv, pt[4]);
            pt[5] = fmaf(w1v[r], hxx, pt[5]);
            pt[6] = fmaf(w1v[r], hyy, pt[6]);
            pt[7] = fmaf(w1v[r], hzz, pt[7]);
        }
    }
    #pragma unroll
    for (int k = 0; k < 8; ++k) {
        pt[k] += __shfl_xor(pt[k], 16, 64);
        pt[k] += __shfl_xor(pt[k], 32, 64);
    }
    if (qc == 0) {
        *(float4*)&red[w][p][0] = make_float4(pt[0], pt[1], pt[2], pt[3]);
        *(float4*)&red[w][p][4] = make_float4(pt[4], pt[5], pt[6], pt[7]);
    }
    __syncthreads();

    if (tid < 16 && (pbase + tid) < N) {
        const int n = pbase + tid;
        float s8[8] = {0.f, 0.f, 0.f, 0.f, 0.f, 0.f, 0.f, 0.f};
        #pragma unroll
        for (int ww = 0; ww < 4; ++ww)
            #pragma unroll
            for (int k = 0; k < 8; ++k) s8[k] += red[ww][tid][k];
        const float fi = gf[n];
        const float PI = 3.14159265358979323846f;
        const float kw = 2.f * PI * (fi * 500.f + 100.f) / 343.f;
        const float vol = 0.7f * 0.5f * 0.6f;
        const float kk = vol * vol * kw * kw;
        const float cxx = (0.5f * 0.6f) * (0.5f * 0.6f);
        const float cyy = (0.7f * 0.6f) * (0.7f * 0.6f);
        const float czz = (0.7f * 0.5f) * (0.7f * 0.5f);
        const float pr = s8[0] + b4[0];
        const float pim = s8[4] + b4[1];
        out[n]     = 2.0f * (cxx * s8[1] + cyy * s8[2] + czz * s8[3]) + kk * (pr * 2.0f + 0.1f);
        out[N + n] = 1.5f * (cxx * s8[5] + cyy * s8[6] + czz * s8[7]) + kk * (pim * 1.5f - 0.05f);
    }
}

extern "C" void kernel_launch(void* const* d_in, const int* in_sizes, int n_in,
                              void* d_out, int out_size, void* d_ws, size_t ws_size,
                              hipStream_t stream) {
    const float* x = (const float*)d_in[0];
    const float* y = (const float*)d_in[1];
    const float* z = (const float*)d_in[2];
    const float* f = (const float*)d_in[3];
    const float* W1 = (const float*)d_in[4];
    const float* b1 = (const float*)d_in[5];
    const float* W2 = (const float*)d_in[6];
    const float* b2 = (const float*)d_in[7];
    const float* W3 = (const float*)d_in[8];
    const float* b3 = (const float*)d_in[9];
    const float* W4 = (const float*)d_in[10];
    const float* b4 = (const float*)d_in[11];
    float* out = (float*)d_out;
    const int N = in_sizes[0];
    const int grid = (N + PBLK - 1) / PBLK;

    prep_split<<<64, 256, 0, stream>>>(W2, W3, (short8*)d_ws);
    bvp_main<<<grid, 256, 0, stream>>>(x, y, z, f, W1, b1, b2, b3, W4, b4,
                                       (const short8*)d_ws, out, N);
}

// Round 4
// 337.450 us; speedup vs baseline: 12.6674x; 1.5164x over previous
//
#include <hip/hip_runtime.h>
#include <math.h>

// BVP Helmholtz-residual PINN via MFMA, round 4.
// psi = MLP(4 -> 256 -> 256 -> 256 -> 2), tanh. Jet propagation: 7 streams
// {v,dx,dy,dz,dxx,dyy,dzz} per point = 7 GEMM columns, col = s*16 + p.
// Changes vs round 3 (issue-slot-bound at MFMA+VALU = 84%):
//  - SINGLE-term bf16 GEMM (dropped Wlo): halves MFMA issue cycles.
//    Error budget: H-bf16 (2^-9 rel) + W-bf16 (2^-9 rel, independent)
//    ~= 0.031*sqrt(2) ~= 0.045 < 0.079 threshold.
//  - bf16 pack via v_add + v_perm_b32 (round-half-up): ~3 inst / 2 values
//    instead of ~10/value -> cuts repack VALU ~2.5x.
//  - A (weights) in A-frag order in d_ws, read L2->reg, no K-loop barriers.
//  - k-permutation k(q,j)=16(j>>2)+4q+(j&3) on layer-3 so each lane's C
//    accumulators pack directly into its own B fragment (lane-local jet).

typedef __attribute__((ext_vector_type(8))) short short8;
typedef __attribute__((ext_vector_type(4))) float floatx4;
typedef unsigned short ushort_t;
typedef unsigned int uint_t;

#define PBLK 16

__device__ __forceinline__ ushort_t f2bf(float f) {
    uint_t u = __float_as_uint(f);
    return (ushort_t)((u + 0x7FFFu + ((u >> 16) & 1u)) >> 16);  // RNE
}
__device__ __forceinline__ float bf2f(ushort_t h) {
    return __uint_as_float(((uint_t)h) << 16);
}
// pack2bf(f0,f1): {bf16(f0), bf16(f1)} in one u32 (f0 low). Round-half-up:
// differs from RNE only on exact ties (prob ~2^-16) -> accuracy-neutral.
__device__ __forceinline__ uint_t pack2bf(float f0, float f1) {
    uint_t u0 = __float_as_uint(f0) + 0x8000u;
    uint_t u1 = __float_as_uint(f1) + 0x8000u;
    return __builtin_amdgcn_perm(u1, u0, 0x07060302u);
}
__device__ __forceinline__ float fast_tanh(float u) {
    float e = __expf(2.f * u);
    return 1.f - 2.f / (e + 1.f);   // exact at +-inf for finite u
}

// ws: 2 layers x 16 row-tiles x 8 kc x 64 lanes x 16B = 256 KB (hi only).
// A-frag lane (m=lane&15, qa=lane>>4) slot j:
//   layer0 (W2, natural):  col = kc*32 + 8*qa + j
//   layer1 (W3, permuted): col = kc*32 + 16*(j>>2) + 4*qa + (j&3)
__global__ void prep_split(const float* __restrict__ W2, const float* __restrict__ W3,
                           short8* __restrict__ ws) {
    int t16 = blockIdx.x * blockDim.x + threadIdx.x;  // 0..16383
    int lane = t16 & 63;
    int kc = (t16 >> 6) & 7;
    int tt = (t16 >> 9) & 15;
    int l = t16 >> 13;
    const float* W = l ? W3 : W2;
    int row = tt * 16 + (lane & 15);
    int qa = lane >> 4;
    const float* src = W + row * 256 + kc * 32 + (l ? 4 * qa : 8 * qa);
    float4 va = *(const float4*)src;
    float4 vb = *(const float4*)(src + (l ? 16 : 4));
    float v[8] = {va.x, va.y, va.z, va.w, vb.x, vb.y, vb.z, vb.w};
    short8 hi8;
    #pragma unroll
    for (int j = 0; j < 8; ++j) hi8[j] = (short)f2bf(v[j]);   // RNE in prep (runs once)
    ws[l * 8192 + tt * 512 + kc * 64 + lane] = hi8;
}

__global__ __launch_bounds__(256, 2)
void bvp_main(const float* __restrict__ gx, const float* __restrict__ gy,
              const float* __restrict__ gz, const float* __restrict__ gf,
              const float* __restrict__ W1, const float* __restrict__ b1,
              const float* __restrict__ b2, const float* __restrict__ b3,
              const float* __restrict__ W4, const float* __restrict__ b4,
              const short8* __restrict__ wsA, float* __restrict__ out, int N) {
    __shared__ short8 Bsh[7 * 8 * 64];   // 57344 B: B[s][kt][lane]
    __shared__ float red[4][16][8];      // 2 KB cross-wave reduction scratch

    const int tid = threadIdx.x;
    const int w = tid >> 6, lane = tid & 63;
    const int p = lane & 15, qc = lane >> 4;
    const int pbase = blockIdx.x * PBLK;

    // ---------------- layer 1 (VALU) -> B fragments ----------------
    {
        const int pp = tid >> 4, u8 = tid & 15;
        const int pidx = min(pbase + pp, N - 1);
        const float xi = gx[pidx], yi = gy[pidx], zi = gz[pidx], fi = gf[pidx];
        #pragma unroll
        for (int g = 0; g < 2; ++g) {
            float hv[7][8];
            #pragma unroll
            for (int r = 0; r < 8; ++r) {
                const int i = u8 * 16 + g * 8 + r;
                float4 wv = *(const float4*)(W1 + 4 * i);
                float u = fmaf(wv.x, xi, fmaf(wv.y, yi, fmaf(wv.z, zi, fmaf(wv.w, fi, b1[i]))));
                float t = fast_tanh(u), s = 1.f - t * t, c = -2.f * t * s;
                hv[0][r] = t;
                hv[1][r] = s * wv.x; hv[2][r] = s * wv.y; hv[3][r] = s * wv.z;
                hv[4][r] = c * wv.x * wv.x; hv[5][r] = c * wv.y * wv.y; hv[6][r] = c * wv.z * wv.z;
            }
            const int u2 = u8 * 2 + g;               // neurons 8*u2..8*u2+7
            const int kt = u2 >> 2, q = u2 & 3, ln = q * 16 + pp;
            #pragma unroll
            for (int s = 0; s < 7; ++s) {
                union { short8 s8; uint_t u4[4]; } v;
                #pragma unroll
                for (int j = 0; j < 4; ++j)
                    v.u4[j] = pack2bf(hv[s][2 * j], hv[s][2 * j + 1]);
                Bsh[(s * 8 + kt) * 64 + ln] = v.s8;
            }
        }
    }
    __syncthreads();

    floatx4 acc[4][7];   // 4 row-tiles (64 rows) x 7 streams

    auto run_gemm = [&](const short8* __restrict__ A) {
        #pragma unroll
        for (int rt = 0; rt < 4; ++rt)
            #pragma unroll
            for (int ct = 0; ct < 7; ++ct) acc[rt][ct] = (floatx4){0.f, 0.f, 0.f, 0.f};
        short8 a[4];
        #pragma unroll
        for (int rt = 0; rt < 4; ++rt)
            a[rt] = A[(4 * w + rt) * 512 + lane];                  // kc = 0
        #pragma unroll
        for (int kc = 0; kc < 8; ++kc) {
            short8 an[4];
            if (kc < 7) {
                #pragma unroll
                for (int rt = 0; rt < 4; ++rt)
                    an[rt] = A[(4 * w + rt) * 512 + (kc + 1) * 64 + lane];
            }
            short8 b[7];
            #pragma unroll
            for (int ct = 0; ct < 7; ++ct) b[ct] = Bsh[(ct * 8 + kc) * 64 + lane];
            #pragma unroll
            for (int ct = 0; ct < 7; ++ct)
                #pragma unroll
                for (int rt = 0; rt < 4; ++rt)
                    acc[rt][ct] = __builtin_amdgcn_mfma_f32_16x16x32_bf16(a[rt], b[ct], acc[rt][ct], 0, 0, 0);
            if (kc < 7) {
                #pragma unroll
                for (int rt = 0; rt < 4; ++rt) a[rt] = an[rt];
            }
        }
    };

    // ---------------- GEMM 2 ----------------
    run_gemm(wsA);
    __syncthreads();   // all waves done reading layer-2 B

    // ---------------- jet 2 (lane-local) -> new B fragments ----------------
    #pragma unroll
    for (int rt = 0; rt < 4; ++rt) {
        const float4 bb = *(const float4*)(b2 + w * 64 + rt * 16 + qc * 4);
        const float bbv[4] = {bb.x, bb.y, bb.z, bb.w};
        #pragma unroll
        for (int r = 0; r < 4; ++r) {
            float t = fast_tanh(acc[rt][0][r] + bbv[r]);
            float s = 1.f - t * t, c = -2.f * t * s;
            float ux = acc[rt][1][r], uy = acc[rt][2][r], uz = acc[rt][3][r];
            acc[rt][0][r] = t;
            acc[rt][1][r] = s * ux; acc[rt][2][r] = s * uy; acc[rt][3][r] = s * uz;
            acc[rt][4][r] = fmaf(s, acc[rt][4][r], c * ux * ux);
            acc[rt][5][r] = fmaf(s, acc[rt][5][r], c * uy * uy);
            acc[rt][6][r] = fmaf(s, acc[rt][6][r], c * uz * uz);
        }
    }
    #pragma unroll
    for (int hh = 0; hh < 2; ++hh)
        #pragma unroll
        for (int s = 0; s < 7; ++s) {
            union { short8 s8; uint_t u4[4]; } v;
            v.u4[0] = pack2bf(acc[2 * hh][s][0], acc[2 * hh][s][1]);
            v.u4[1] = pack2bf(acc[2 * hh][s][2], acc[2 * hh][s][3]);
            v.u4[2] = pack2bf(acc[2 * hh + 1][s][0], acc[2 * hh + 1][s][1]);
            v.u4[3] = pack2bf(acc[2 * hh + 1][s][2], acc[2 * hh + 1][s][3]);
            Bsh[(s * 8 + 2 * w + hh) * 64 + lane] = v.s8;   // kt = 2w+hh, own lane slot
        }
    __syncthreads();

    // ---------------- GEMM 3 ----------------
    run_gemm(wsA + 8192);

    // ---------------- jet 3 + layer-4 partials (lane-local) ----------------
    float pt[8] = {0.f, 0.f, 0.f, 0.f, 0.f, 0.f, 0.f, 0.f};
    #pragma unroll
    for (int rt = 0; rt < 4; ++rt) {
        const int rb = w * 64 + rt * 16 + qc * 4;
        const float4 bb = *(const float4*)(b3 + rb);
        const float4 w0 = *(const float4*)(W4 + rb);
        const float4 w1 = *(const float4*)(W4 + 256 + rb);
        const float bbv[4] = {bb.x, bb.y, bb.z, bb.w};
        const float w0v[4] = {w0.x, w0.y, w0.z, w0.w};
        const float w1v[4] = {w1.x, w1.y, w1.z, w1.w};
        #pragma unroll
        for (int r = 0; r < 4; ++r) {
            float t = fast_tanh(acc[rt][0][r] + bbv[r]);
            float s = 1.f - t * t, c = -2.f * t * s;
            float ux = acc[rt][1][r], uy = acc[rt][2][r], uz = acc[rt][3][r];
            float hv = t;
            float hxx = fmaf(s, acc[rt][4][r], c * ux * ux);
            float hyy = fmaf(s, acc[rt][5][r], c * uy * uy);
            float hzz = fmaf(s, acc[rt][6][r], c * uz * uz);
            pt[0] = fmaf(w0v[r], hv, pt[0]);
            pt[1] = fmaf(w0v[r], hxx, pt[1]);
            pt[2] = fmaf(w0v[r], hyy, pt[2]);
            pt[3] = fmaf(w0v[r], hzz, pt[3]);
            pt[4] = fmaf(w1v[r], hv, pt[4]);
            pt[5] = fmaf(w1v[r], hxx, pt[5]);
            pt[6] = fmaf(w1v[r], hyy, pt[6]);
            pt[7] = fmaf(w1v[r], hzz, pt[7]);
        }
    }
    #pragma unroll
    for (int k = 0; k < 8; ++k) {
        pt[k] += __shfl_xor(pt[k], 16, 64);
        pt[k] += __shfl_xor(pt[k], 32, 64);
    }
    if (qc == 0) {
        *(float4*)&red[w][p][0] = make_float4(pt[0], pt[1], pt[2], pt[3]);
        *(float4*)&red[w][p][4] = make_float4(pt[4], pt[5], pt[6], pt[7]);
    }
    __syncthreads();

    if (tid < 16 && (pbase + tid) < N) {
        const int n = pbase + tid;
        float s8[8] = {0.f, 0.f, 0.f, 0.f, 0.f, 0.f, 0.f, 0.f};
        #pragma unroll
        for (int ww = 0; ww < 4; ++ww)
            #pragma unroll
            for (int k = 0; k < 8; ++k) s8[k] += red[ww][tid][k];
        const float fi = gf[n];
        const float PI = 3.14159265358979323846f;
        const float kw = 2.f * PI * (fi * 500.f + 100.f) / 343.f;
        const float vol = 0.7f * 0.5f * 0.6f;
        const float kk = vol * vol * kw * kw;
        const float cxx = (0.5f * 0.6f) * (0.5f * 0.6f);
        const float cyy = (0.7f * 0.6f) * (0.7f * 0.6f);
        const float czz = (0.7f * 0.5f) * (0.7f * 0.5f);
        const float pr = s8[0] + b4[0];
        const float pim = s8[4] + b4[1];
        out[n]     = 2.0f * (cxx * s8[1] + cyy * s8[2] + czz * s8[3]) + kk * (pr * 2.0f + 0.1f);
        out[N + n] = 1.5f * (cxx * s8[5] + cyy * s8[6] + czz * s8[7]) + kk * (pim * 1.5f - 0.05f);
    }
}

extern "C" void kernel_launch(void* const* d_in, const int* in_sizes, int n_in,
                              void* d_out, int out_size, void* d_ws, size_t ws_size,
                              hipStream_t stream) {
    const float* x = (const float*)d_in[0];
    const float* y = (const float*)d_in[1];
    const float* z = (const float*)d_in[2];
    const float* f = (const float*)d_in[3];
    const float* W1 = (const float*)d_in[4];
    const float* b1 = (const float*)d_in[5];
    const float* W2 = (const float*)d_in[6];
    const float* b2 = (const float*)d_in[7];
    const float* W3 = (const float*)d_in[8];
    const float* b3 = (const float*)d_in[9];
    const float* W4 = (const float*)d_in[10];
    const float* b4 = (const float*)d_in[11];
    float* out = (float*)d_out;
    const int N = in_sizes[0];
    const int grid = (N + PBLK - 1) / PBLK;

    prep_split<<<64, 256, 0, stream>>>(W2, W3, (short8*)d_ws);
    bvp_main<<<grid, 256, 0, stream>>>(x, y, z, f, W1, b1, b2, b3, W4, b4,
                                       (const short8*)d_ws, out, N);
}

// Round 5
// 334.950 us; speedup vs baseline: 12.7619x; 1.0075x over previous
//
#include <hip/hip_runtime.h>
#include <math.h>

// BVP Helmholtz-residual PINN via MFMA, round 5.
// psi = MLP(4 -> 256 -> 256 -> 256 -> 2), tanh. Jet propagation: 7 streams
// {v,dx,dy,dz,dxx,dyy,dzz} per point = 7 GEMM columns, col = s*16 + p.
// Round-4 counters decoded: MfmaUtil/VALUBusy are CU-level (4x per-SIMD);
// true pipe utilizations ~9%/~15% -> latency-bound at 2 waves/SIMD.
// Round-5 changes (ILP, not TLP — W=8 would double B-LDS traffic to 144us):
//  - A-fragment global prefetch 2 kc deep (covers ~260cyc L2 latency).
//  - B LDS reads double-buffered in regs (kc+1 reads before kc MFMAs).
//  - GEMM-2 A(kc0,1) loads issued at kernel start (covered by layer-1);
//    GEMM-3 A(kc0,1) issued before jet-2 math (covered by jet + barrier).
// VGPR rises to ~230 — fine: LDS (59KB -> 2 blocks/CU) is the occupancy cap,
// and 2 waves/SIMD permits 256 VGPR.

typedef __attribute__((ext_vector_type(8))) short short8;
typedef __attribute__((ext_vector_type(4))) float floatx4;
typedef unsigned short ushort_t;
typedef unsigned int uint_t;

#define PBLK 16

__device__ __forceinline__ ushort_t f2bf(float f) {
    uint_t u = __float_as_uint(f);
    return (ushort_t)((u + 0x7FFFu + ((u >> 16) & 1u)) >> 16);  // RNE
}
// pack2bf(f0,f1): {bf16(f0), bf16(f1)} in one u32 (f0 low). Round-half-up.
__device__ __forceinline__ uint_t pack2bf(float f0, float f1) {
    uint_t u0 = __float_as_uint(f0) + 0x8000u;
    uint_t u1 = __float_as_uint(f1) + 0x8000u;
    return __builtin_amdgcn_perm(u1, u0, 0x07060302u);
}
__device__ __forceinline__ float fast_tanh(float u) {
    float e = __expf(2.f * u);
    return 1.f - 2.f / (e + 1.f);   // exact at +-inf for finite u
}

// ws: 2 layers x 16 row-tiles x 8 kc x 64 lanes x 16B = 256 KB.
// A-frag lane (m=lane&15, qa=lane>>4) slot j:
//   layer0 (W2, natural):  col = kc*32 + 8*qa + j
//   layer1 (W3, permuted): col = kc*32 + 16*(j>>2) + 4*qa + (j&3)
__global__ void prep_split(const float* __restrict__ W2, const float* __restrict__ W3,
                           short8* __restrict__ ws) {
    int t16 = blockIdx.x * blockDim.x + threadIdx.x;  // 0..16383
    int lane = t16 & 63;
    int kc = (t16 >> 6) & 7;
    int tt = (t16 >> 9) & 15;
    int l = t16 >> 13;
    const float* W = l ? W3 : W2;
    int row = tt * 16 + (lane & 15);
    int qa = lane >> 4;
    const float* src = W + row * 256 + kc * 32 + (l ? 4 * qa : 8 * qa);
    float4 va = *(const float4*)src;
    float4 vb = *(const float4*)(src + (l ? 16 : 4));
    float v[8] = {va.x, va.y, va.z, va.w, vb.x, vb.y, vb.z, vb.w};
    short8 hi8;
    #pragma unroll
    for (int j = 0; j < 8; ++j) hi8[j] = (short)f2bf(v[j]);   // RNE (runs once)
    ws[l * 8192 + tt * 512 + kc * 64 + lane] = hi8;
}

__global__ __launch_bounds__(256, 2)
void bvp_main(const float* __restrict__ gx, const float* __restrict__ gy,
              const float* __restrict__ gz, const float* __restrict__ gf,
              const float* __restrict__ W1, const float* __restrict__ b1,
              const float* __restrict__ b2, const float* __restrict__ b3,
              const float* __restrict__ W4, const float* __restrict__ b4,
              const short8* __restrict__ wsA, float* __restrict__ out, int N) {
    __shared__ short8 Bsh[7 * 8 * 64];   // 57344 B: B[s][kt][lane]
    __shared__ float red[4][16][8];      // 2 KB cross-wave reduction scratch

    const int tid = threadIdx.x;
    const int w = tid >> 6, lane = tid & 63;
    const int p = lane & 15, qc = lane >> 4;
    const int pbase = blockIdx.x * PBLK;
    const short8* __restrict__ wsA3 = wsA + 8192;

    floatx4 acc[4][7];   // 4 row-tiles (64 rows) x 7 streams
    short8 a0[4], a1[4];

    // GEMM-2 A(kc=0,1): issue NOW, covered by all of layer-1.
    #pragma unroll
    for (int rt = 0; rt < 4; ++rt) {
        a0[rt] = wsA[(4 * w + rt) * 512 + lane];
        a1[rt] = wsA[(4 * w + rt) * 512 + 64 + lane];
    }

    // ---------------- layer 1 (VALU) -> B fragments ----------------
    {
        const int pp = tid >> 4, u8 = tid & 15;
        const int pidx = min(pbase + pp, N - 1);
        const float xi = gx[pidx], yi = gy[pidx], zi = gz[pidx], fi = gf[pidx];
        #pragma unroll
        for (int g = 0; g < 2; ++g) {
            float hv[7][8];
            #pragma unroll
            for (int r = 0; r < 8; ++r) {
                const int i = u8 * 16 + g * 8 + r;
                float4 wv = *(const float4*)(W1 + 4 * i);
                float u = fmaf(wv.x, xi, fmaf(wv.y, yi, fmaf(wv.z, zi, fmaf(wv.w, fi, b1[i]))));
                float t = fast_tanh(u), s = 1.f - t * t, c = -2.f * t * s;
                hv[0][r] = t;
                hv[1][r] = s * wv.x; hv[2][r] = s * wv.y; hv[3][r] = s * wv.z;
                hv[4][r] = c * wv.x * wv.x; hv[5][r] = c * wv.y * wv.y; hv[6][r] = c * wv.z * wv.z;
            }
            const int u2 = u8 * 2 + g;               // neurons 8*u2..8*u2+7
            const int kt = u2 >> 2, q = u2 & 3, ln = q * 16 + pp;
            #pragma unroll
            for (int s = 0; s < 7; ++s) {
                union { short8 s8; uint_t u4[4]; } v;
                #pragma unroll
                for (int j = 0; j < 4; ++j)
                    v.u4[j] = pack2bf(hv[s][2 * j], hv[s][2 * j + 1]);
                Bsh[(s * 8 + kt) * 64 + ln] = v.s8;
            }
        }
    }
    __syncthreads();

    // run_gemm: deep-pipelined K-loop. a0/a1 preloaded by caller (kc=0,1);
    // inside: A 2-deep global prefetch, B double-buffered LDS reads.
    auto run_gemm = [&](const short8* __restrict__ A) {
        #pragma unroll
        for (int rt = 0; rt < 4; ++rt)
            #pragma unroll
            for (int ct = 0; ct < 7; ++ct) acc[rt][ct] = (floatx4){0.f, 0.f, 0.f, 0.f};
        short8 b0[7], b1[7];
        #pragma unroll
        for (int ct = 0; ct < 7; ++ct) b0[ct] = Bsh[(ct * 8) * 64 + lane];
        #pragma unroll
        for (int kc = 0; kc < 8; ++kc) {
            if (kc < 7) {
                #pragma unroll
                for (int ct = 0; ct < 7; ++ct) b1[ct] = Bsh[(ct * 8 + kc + 1) * 64 + lane];
            }
            short8 a2[4];
            if (kc < 6) {
                #pragma unroll
                for (int rt = 0; rt < 4; ++rt)
                    a2[rt] = A[(4 * w + rt) * 512 + (kc + 2) * 64 + lane];
            }
            #pragma unroll
            for (int ct = 0; ct < 7; ++ct)
                #pragma unroll
                for (int rt = 0; rt < 4; ++rt)
                    acc[rt][ct] = __builtin_amdgcn_mfma_f32_16x16x32_bf16(a0[rt], b0[ct], acc[rt][ct], 0, 0, 0);
            #pragma unroll
            for (int rt = 0; rt < 4; ++rt) {
                a0[rt] = a1[rt];
                if (kc < 6) a1[rt] = a2[rt];
            }
            #pragma unroll
            for (int ct = 0; ct < 7; ++ct) b0[ct] = b1[ct];
        }
    };

    // ---------------- GEMM 2 ----------------
    run_gemm(wsA);
    __syncthreads();   // all waves done reading layer-2 B

    // GEMM-3 A(kc=0,1): issue NOW, covered by jet-2 math + barrier.
    #pragma unroll
    for (int rt = 0; rt < 4; ++rt) {
        a0[rt] = wsA3[(4 * w + rt) * 512 + lane];
        a1[rt] = wsA3[(4 * w + rt) * 512 + 64 + lane];
    }

    // ---------------- jet 2 (lane-local) -> new B fragments ----------------
    #pragma unroll
    for (int rt = 0; rt < 4; ++rt) {
        const float4 bb = *(const float4*)(b2 + w * 64 + rt * 16 + qc * 4);
        const float bbv[4] = {bb.x, bb.y, bb.z, bb.w};
        #pragma unroll
        for (int r = 0; r < 4; ++r) {
            float t = fast_tanh(acc[rt][0][r] + bbv[r]);
            float s = 1.f - t * t, c = -2.f * t * s;
            float ux = acc[rt][1][r], uy = acc[rt][2][r], uz = acc[rt][3][r];
            acc[rt][0][r] = t;
            acc[rt][1][r] = s * ux; acc[rt][2][r] = s * uy; acc[rt][3][r] = s * uz;
            acc[rt][4][r] = fmaf(s, acc[rt][4][r], c * ux * ux);
            acc[rt][5][r] = fmaf(s, acc[rt][5][r], c * uy * uy);
            acc[rt][6][r] = fmaf(s, acc[rt][6][r], c * uz * uz);
        }
    }
    #pragma unroll
    for (int hh = 0; hh < 2; ++hh)
        #pragma unroll
        for (int s = 0; s < 7; ++s) {
            union { short8 s8; uint_t u4[4]; } v;
            v.u4[0] = pack2bf(acc[2 * hh][s][0], acc[2 * hh][s][1]);
            v.u4[1] = pack2bf(acc[2 * hh][s][2], acc[2 * hh][s][3]);
            v.u4[2] = pack2bf(acc[2 * hh + 1][s][0], acc[2 * hh + 1][s][1]);
            v.u4[3] = pack2bf(acc[2 * hh + 1][s][2], acc[2 * hh + 1][s][3]);
            Bsh[(s * 8 + 2 * w + hh) * 64 + lane] = v.s8;   // kt = 2w+hh, own lane slot
        }
    __syncthreads();

    // ---------------- GEMM 3 ----------------
    run_gemm(wsA3);

    // ---------------- jet 3 + layer-4 partials (lane-local) ----------------
    float pt[8] = {0.f, 0.f, 0.f, 0.f, 0.f, 0.f, 0.f, 0.f};
    #pragma unroll
    for (int rt = 0; rt < 4; ++rt) {
        const int rb = w * 64 + rt * 16 + qc * 4;
        const float4 bb = *(const float4*)(b3 + rb);
        const float4 w0 = *(const float4*)(W4 + rb);
        const float4 w1 = *(const float4*)(W4 + 256 + rb);
        const float bbv[4] = {bb.x, bb.y, bb.z, bb.w};
        const float w0v[4] = {w0.x, w0.y, w0.z, w0.w};
        const float w1v[4] = {w1.x, w1.y, w1.z, w1.w};
        #pragma unroll
        for (int r = 0; r < 4; ++r) {
            float t = fast_tanh(acc[rt][0][r] + bbv[r]);
            float s = 1.f - t * t, c = -2.f * t * s;
            float ux = acc[rt][1][r], uy = acc[rt][2][r], uz = acc[rt][3][r];
            float hv = t;
            float hxx = fmaf(s, acc[rt][4][r], c * ux * ux);
            float hyy = fmaf(s, acc[rt][5][r], c * uy * uy);
            float hzz = fmaf(s, acc[rt][6][r], c * uz * uz);
            pt[0] = fmaf(w0v[r], hv, pt[0]);
            pt[1] = fmaf(w0v[r], hxx, pt[1]);
            pt[2] = fmaf(w0v[r], hyy, pt[2]);
            pt[3] = fmaf(w0v[r], hzz, pt[3]);
            pt[4] = fmaf(w1v[r], hv, pt[4]);
            pt[5] = fmaf(w1v[r], hxx, pt[5]);
            pt[6] = fmaf(w1v[r], hyy, pt[6]);
            pt[7] = fmaf(w1v[r], hzz, pt[7]);
        }
    }
    #pragma unroll
    for (int k = 0; k < 8; ++k) {
        pt[k] += __shfl_xor(pt[k], 16, 64);
        pt[k] += __shfl_xor(pt[k], 32, 64);
    }
    if (qc == 0) {
        *(float4*)&red[w][p][0] = make_float4(pt[0], pt[1], pt[2], pt[3]);
        *(float4*)&red[w][p][4] = make_float4(pt[4], pt[5], pt[6], pt[7]);
    }
    __syncthreads();

    if (tid < 16 && (pbase + tid) < N) {
        const int n = pbase + tid;
        float s8[8] = {0.f, 0.f, 0.f, 0.f, 0.f, 0.f, 0.f, 0.f};
        #pragma unroll
        for (int ww = 0; ww < 4; ++ww)
            #pragma unroll
            for (int k = 0; k < 8; ++k) s8[k] += red[ww][tid][k];
        const float fi = gf[n];
        const float PI = 3.14159265358979323846f;
        const float kw = 2.f * PI * (fi * 500.f + 100.f) / 343.f;
        const float vol = 0.7f * 0.5f * 0.6f;
        const float kk = vol * vol * kw * kw;
        const float cxx = (0.5f * 0.6f) * (0.5f * 0.6f);
        const float cyy = (0.7f * 0.6f) * (0.7f * 0.6f);
        const float czz = (0.7f * 0.5f) * (0.7f * 0.5f);
        const float pr = s8[0] + b4[0];
        const float pim = s8[4] + b4[1];
        out[n]     = 2.0f * (cxx * s8[1] + cyy * s8[2] + czz * s8[3]) + kk * (pr * 2.0f + 0.1f);
        out[N + n] = 1.5f * (cxx * s8[5] + cyy * s8[6] + czz * s8[7]) + kk * (pim * 1.5f - 0.05f);
    }
}

extern "C" void kernel_launch(void* const* d_in, const int* in_sizes, int n_in,
                              void* d_out, int out_size, void* d_ws, size_t ws_size,
                              hipStream_t stream) {
    const float* x = (const float*)d_in[0];
    const float* y = (const float*)d_in[1];
    const float* z = (const float*)d_in[2];
    const float* f = (const float*)d_in[3];
    const float* W1 = (const float*)d_in[4];
    const float* b1 = (const float*)d_in[5];
    const float* W2 = (const float*)d_in[6];
    const float* b2 = (const float*)d_in[7];
    const float* W3 = (const float*)d_in[8];
    const float* b3 = (const float*)d_in[9];
    const float* W4 = (const float*)d_in[10];
    const float* b4 = (const float*)d_in[11];
    float* out = (float*)d_out;
    const int N = in_sizes[0];
    const int grid = (N + PBLK - 1) / PBLK;

    prep_split<<<64, 256, 0, stream>>>(W2, W3, (short8*)d_ws);
    bvp_main<<<grid, 256, 0, stream>>>(x, y, z, f, W1, b1, b2, b3, W4, b4,
                                       (const short8*)d_ws, out, N);
}

// Round 6
// 316.315 us; speedup vs baseline: 13.5138x; 1.0589x over previous
//
#include <hip/hip_runtime.h>
#include <math.h>

// BVP Helmholtz-residual PINN via MFMA, round 6.
// psi = MLP(4 -> 256 -> 256 -> 256 -> 2), tanh. Jet propagation: 7 streams
// {v,dx,dy,dz,dxx,dyy,dzz} per point = 7 GEMM columns, col = s*16 + p.
// Round-5 post-mortem: manual ILP was NEUTRAL; waves ~80% idle at 2/SIMD ->
// latency-bound on TLP, plus 2.58e7 LDS bank-conflict cycles from layer-1
// B-writes (point index in high lane bits -> same-bank 16/32-way).
// Round-6 changes:
//  - 512 threads / 8 waves x 32 rows (2 row-tiles): 4 waves/SIMD (2x TLP).
//    __launch_bounds__(512,4) caps VGPR at 128 (acc halves to 56 regs).
//  - layer-1 remap pp=tid&15, u8=tid>>4: each 16-lane group writes one
//    contiguous 256B chunk -> zero bank conflicts; W1 rows broadcast.
//  - same A-from-L2 (no K-loop barriers), same k-permutation lane-local jet.

typedef __attribute__((ext_vector_type(8))) short short8;
typedef __attribute__((ext_vector_type(4))) float floatx4;
typedef unsigned short ushort_t;
typedef unsigned int uint_t;

#define PBLK 16

__device__ __forceinline__ ushort_t f2bf(float f) {
    uint_t u = __float_as_uint(f);
    return (ushort_t)((u + 0x7FFFu + ((u >> 16) & 1u)) >> 16);  // RNE
}
// pack2bf(f0,f1): {bf16(f0), bf16(f1)} in one u32 (f0 low). Round-half-up.
__device__ __forceinline__ uint_t pack2bf(float f0, float f1) {
    uint_t u0 = __float_as_uint(f0) + 0x8000u;
    uint_t u1 = __float_as_uint(f1) + 0x8000u;
    return __builtin_amdgcn_perm(u1, u0, 0x07060302u);
}
__device__ __forceinline__ float fast_tanh(float u) {
    float e = __expf(2.f * u);
    return 1.f - 2.f / (e + 1.f);   // exact at +-inf for finite u
}

// ws: 2 layers x 16 row-tiles x 8 kc x 64 lanes x 16B = 256 KB.
// A-frag lane (m=lane&15, qa=lane>>4) slot j:
//   layer0 (W2, natural):  col = kc*32 + 8*qa + j
//   layer1 (W3, permuted): col = kc*32 + 16*(j>>2) + 4*qa + (j&3)
__global__ void prep_split(const float* __restrict__ W2, const float* __restrict__ W3,
                           short8* __restrict__ ws) {
    int t16 = blockIdx.x * blockDim.x + threadIdx.x;  // 0..16383
    int lane = t16 & 63;
    int kc = (t16 >> 6) & 7;
    int tt = (t16 >> 9) & 15;
    int l = t16 >> 13;
    const float* W = l ? W3 : W2;
    int row = tt * 16 + (lane & 15);
    int qa = lane >> 4;
    const float* src = W + row * 256 + kc * 32 + (l ? 4 * qa : 8 * qa);
    float4 va = *(const float4*)src;
    float4 vb = *(const float4*)(src + (l ? 16 : 4));
    float v[8] = {va.x, va.y, va.z, va.w, vb.x, vb.y, vb.z, vb.w};
    short8 hi8;
    #pragma unroll
    for (int j = 0; j < 8; ++j) hi8[j] = (short)f2bf(v[j]);   // RNE (runs once)
    ws[l * 8192 + tt * 512 + kc * 64 + lane] = hi8;
}

__global__ __launch_bounds__(512, 4)
void bvp_main(const float* __restrict__ gx, const float* __restrict__ gy,
              const float* __restrict__ gz, const float* __restrict__ gf,
              const float* __restrict__ W1, const float* __restrict__ b1,
              const float* __restrict__ b2, const float* __restrict__ b3,
              const float* __restrict__ W4, const float* __restrict__ b4,
              const short8* __restrict__ wsA, float* __restrict__ out, int N) {
    __shared__ short8 Bsh[7 * 8 * 64];   // 57344 B: B[s][kt][lane]
    __shared__ float red[8][16][8];      // 4 KB cross-wave reduction scratch

    const int tid = threadIdx.x;
    const int w = tid >> 6, lane = tid & 63;
    const int n15 = lane & 15, qc = lane >> 4;
    const int pbase = blockIdx.x * PBLK;
    const short8* __restrict__ wsA3 = wsA + 8192;

    floatx4 acc[2][7];   // 2 row-tiles (32 rows) x 7 streams
    short8 a0[2], a1[2];

    // GEMM-2 A(kc=0): issue now, covered by layer-1 math.
    #pragma unroll
    for (int rt = 0; rt < 2; ++rt) a0[rt] = wsA[(2 * w + rt) * 512 + lane];

    // ---------------- layer 1 (VALU) -> B fragments ----------------
    // pp = tid&15: 16-lane groups write contiguous 256B -> conflict-free;
    // threads sharing u8 read the same W1 rows (broadcast).
    {
        const int pp = tid & 15, u8 = tid >> 4;     // u8 in 0..31: neurons 8*u8..+7
        const int pidx = min(pbase + pp, N - 1);
        const float xi = gx[pidx], yi = gy[pidx], zi = gz[pidx], fi = gf[pidx];
        float hv[7][8];
        #pragma unroll
        for (int r = 0; r < 8; ++r) {
            const int i = u8 * 8 + r;
            float4 wv = *(const float4*)(W1 + 4 * i);
            float u = fmaf(wv.x, xi, fmaf(wv.y, yi, fmaf(wv.z, zi, fmaf(wv.w, fi, b1[i]))));
            float t = fast_tanh(u), s = 1.f - t * t, c = -2.f * t * s;
            hv[0][r] = t;
            hv[1][r] = s * wv.x; hv[2][r] = s * wv.y; hv[3][r] = s * wv.z;
            hv[4][r] = c * wv.x * wv.x; hv[5][r] = c * wv.y * wv.y; hv[6][r] = c * wv.z * wv.z;
        }
        const int kt = u8 >> 2, qb = u8 & 3;        // k-slot qb*8+r (natural order)
        #pragma unroll
        for (int s = 0; s < 7; ++s) {
            union { short8 s8; uint_t u4[4]; } v;
            #pragma unroll
            for (int j = 0; j < 4; ++j)
                v.u4[j] = pack2bf(hv[s][2 * j], hv[s][2 * j + 1]);
            Bsh[(s * 8 + kt) * 64 + qb * 16 + pp] = v.s8;
        }
    }
    __syncthreads();

    // K-loop: A 1-deep global prefetch (L2-resident), B single-buffer LDS.
    auto run_gemm = [&](const short8* __restrict__ A) {
        #pragma unroll
        for (int rt = 0; rt < 2; ++rt)
            #pragma unroll
            for (int ct = 0; ct < 7; ++ct) acc[rt][ct] = (floatx4){0.f, 0.f, 0.f, 0.f};
        #pragma unroll
        for (int kc = 0; kc < 8; ++kc) {
            if (kc < 7) {
                #pragma unroll
                for (int rt = 0; rt < 2; ++rt)
                    a1[rt] = A[(2 * w + rt) * 512 + (kc + 1) * 64 + lane];
            }
            short8 b[7];
            #pragma unroll
            for (int ct = 0; ct < 7; ++ct) b[ct] = Bsh[(ct * 8 + kc) * 64 + lane];
            #pragma unroll
            for (int ct = 0; ct < 7; ++ct)
                #pragma unroll
                for (int rt = 0; rt < 2; ++rt)
                    acc[rt][ct] = __builtin_amdgcn_mfma_f32_16x16x32_bf16(a0[rt], b[ct], acc[rt][ct], 0, 0, 0);
            if (kc < 7) {
                #pragma unroll
                for (int rt = 0; rt < 2; ++rt) a0[rt] = a1[rt];
            }
        }
    };

    // ---------------- GEMM 2 ----------------
    run_gemm(wsA);
    __syncthreads();   // all waves done reading layer-2 B

    // GEMM-3 A(kc=0): issue now, covered by jet-2 math.
    #pragma unroll
    for (int rt = 0; rt < 2; ++rt) a0[rt] = wsA3[(2 * w + rt) * 512 + lane];

    // ---------------- jet 2 (lane-local) -> new B fragments ----------------
    // Wave w's 32 rows are exactly k-tile w; permuted k-order
    // k(qc,j)=16(j>>2)+4qc+(j&3) makes the repack lane-local.
    #pragma unroll
    for (int rt = 0; rt < 2; ++rt) {
        const float4 bb = *(const float4*)(b2 + w * 32 + rt * 16 + qc * 4);
        const float bbv[4] = {bb.x, bb.y, bb.z, bb.w};
        #pragma unroll
        for (int r = 0; r < 4; ++r) {
            float t = fast_tanh(acc[rt][0][r] + bbv[r]);
            float s = 1.f - t * t, c = -2.f * t * s;
            float ux = acc[rt][1][r], uy = acc[rt][2][r], uz = acc[rt][3][r];
            acc[rt][0][r] = t;
            acc[rt][1][r] = s * ux; acc[rt][2][r] = s * uy; acc[rt][3][r] = s * uz;
            acc[rt][4][r] = fmaf(s, acc[rt][4][r], c * ux * ux);
            acc[rt][5][r] = fmaf(s, acc[rt][5][r], c * uy * uy);
            acc[rt][6][r] = fmaf(s, acc[rt][6][r], c * uz * uz);
        }
    }
    #pragma unroll
    for (int s = 0; s < 7; ++s) {
        union { short8 s8; uint_t u4[4]; } v;
        v.u4[0] = pack2bf(acc[0][s][0], acc[0][s][1]);
        v.u4[1] = pack2bf(acc[0][s][2], acc[0][s][3]);
        v.u4[2] = pack2bf(acc[1][s][0], acc[1][s][1]);
        v.u4[3] = pack2bf(acc[1][s][2], acc[1][s][3]);
        Bsh[(s * 8 + w) * 64 + lane] = v.s8;   // kt = w, own lane slot
    }
    __syncthreads();

    // ---------------- GEMM 3 ----------------
    run_gemm(wsA3);

    // ---------------- jet 3 + layer-4 partials (lane-local) ----------------
    float pt[8] = {0.f, 0.f, 0.f, 0.f, 0.f, 0.f, 0.f, 0.f};
    #pragma unroll
    for (int rt = 0; rt < 2; ++rt) {
        const int rb = w * 32 + rt * 16 + qc * 4;
        const float4 bb = *(const float4*)(b3 + rb);
        const float4 w0 = *(const float4*)(W4 + rb);
        const float4 w1 = *(const float4*)(W4 + 256 + rb);
        const float bbv[4] = {bb.x, bb.y, bb.z, bb.w};
        const float w0v[4] = {w0.x, w0.y, w0.z, w0.w};
        const float w1v[4] = {w1.x, w1.y, w1.z, w1.w};
        #pragma unroll
        for (int r = 0; r < 4; ++r) {
            float t = fast_tanh(acc[rt][0][r] + bbv[r]);
            float s = 1.f - t * t, c = -2.f * t * s;
            float ux = acc[rt][1][r], uy = acc[rt][2][r], uz = acc[rt][3][r];
            float hv = t;
            float hxx = fmaf(s, acc[rt][4][r], c * ux * ux);
            float hyy = fmaf(s, acc[rt][5][r], c * uy * uy);
            float hzz = fmaf(s, acc[rt][6][r], c * uz * uz);
            pt[0] = fmaf(w0v[r], hv, pt[0]);
            pt[1] = fmaf(w0v[r], hxx, pt[1]);
            pt[2] = fmaf(w0v[r], hyy, pt[2]);
            pt[3] = fmaf(w0v[r], hzz, pt[3]);
            pt[4] = fmaf(w1v[r], hv, pt[4]);
            pt[5] = fmaf(w1v[r], hxx, pt[5]);
            pt[6] = fmaf(w1v[r], hyy, pt[6]);
            pt[7] = fmaf(w1v[r], hzz, pt[7]);
        }
    }
    #pragma unroll
    for (int k = 0; k < 8; ++k) {
        pt[k] += __shfl_xor(pt[k], 16, 64);
        pt[k] += __shfl_xor(pt[k], 32, 64);
    }
    if (qc == 0) {
        *(float4*)&red[w][n15][0] = make_float4(pt[0], pt[1], pt[2], pt[3]);
        *(float4*)&red[w][n15][4] = make_float4(pt[4], pt[5], pt[6], pt[7]);
    }
    __syncthreads();

    if (tid < 16 && (pbase + tid) < N) {
        const int n = pbase + tid;
        float s8[8] = {0.f, 0.f, 0.f, 0.f, 0.f, 0.f, 0.f, 0.f};
        #pragma unroll
        for (int ww = 0; ww < 8; ++ww)
            #pragma unroll
            for (int k = 0; k < 8; ++k) s8[k] += red[ww][tid][k];
        const float fi = gf[n];
        const float PI = 3.14159265358979323846f;
        const float kw = 2.f * PI * (fi * 500.f + 100.f) / 343.f;
        const float vol = 0.7f * 0.5f * 0.6f;
        const float kk = vol * vol * kw * kw;
        const float cxx = (0.5f * 0.6f) * (0.5f * 0.6f);
        const float cyy = (0.7f * 0.6f) * (0.7f * 0.6f);
        const float czz = (0.7f * 0.5f) * (0.7f * 0.5f);
        const float pr = s8[0] + b4[0];
        const float pim = s8[4] + b4[1];
        out[n]     = 2.0f * (cxx * s8[1] + cyy * s8[2] + czz * s8[3]) + kk * (pr * 2.0f + 0.1f);
        out[N + n] = 1.5f * (cxx * s8[5] + cyy * s8[6] + czz * s8[7]) + kk * (pim * 1.5f - 0.05f);
    }
}

extern "C" void kernel_launch(void* const* d_in, const int* in_sizes, int n_in,
                              void* d_out, int out_size, void* d_ws, size_t ws_size,
                              hipStream_t stream) {
    const float* x = (const float*)d_in[0];
    const float* y = (const float*)d_in[1];
    const float* z = (const float*)d_in[2];
    const float* f = (const float*)d_in[3];
    const float* W1 = (const float*)d_in[4];
    const float* b1 = (const float*)d_in[5];
    const float* W2 = (const float*)d_in[6];
    const float* b2 = (const float*)d_in[7];
    const float* W3 = (const float*)d_in[8];
    const float* b3 = (const float*)d_in[9];
    const float* W4 = (const float*)d_in[10];
    const float* b4 = (const float*)d_in[11];
    float* out = (float*)d_out;
    const int N = in_sizes[0];
    const int grid = (N + PBLK - 1) / PBLK;

    prep_split<<<64, 256, 0, stream>>>(W2, W3, (short8*)d_ws);
    bvp_main<<<grid, 512, 0, stream>>>(x, y, z, f, W1, b1, b2, b3, W4, b4,
                                       (const short8*)d_ws, out, N);
}